// Round 6
// baseline (686.587 us; speedup 1.0000x reference)
//
#include <hip/hip_runtime.h>
#include <hip/hip_bf16.h>

#define BETA_C 0.04f
#define EPS_LOW_C 0.2f
#define EPS_HIGH_C 0.2f

static constexpr int B_ = 4, S_ = 1024, H_ = 2048, V_ = 32000;
static constexpr int M_ = B_ * S_;          // 4096 token rows
static constexpr int BM = 256, BN = 256, BK = 64;
static constexpr int NRB = M_ / BM;         // 16
static constexpr int NCB = V_ / BN;         // 125
static constexpr int NT  = H_ / BK;         // 32 K-steps

typedef __attribute__((ext_vector_type(8))) short short8;
typedef __attribute__((ext_vector_type(16))) float f32x16;

__device__ __forceinline__ unsigned short f2bf(float f) {
    unsigned u = __builtin_bit_cast(unsigned, f);
    unsigned r = 0x7FFFu + ((u >> 16) & 1u);
    return (unsigned short)((u + r) >> 16);
}

__device__ __forceinline__ void gload_lds16(const unsigned short* g, unsigned short* l) {
    __builtin_amdgcn_global_load_lds(
        (const __attribute__((address_space(1))) unsigned int*)g,
        (__attribute__((address_space(3))) unsigned int*)l, 16, 0, 0);
}

// ---------------- fp32 -> bf16 conversion ----------------
__global__ void cvt_kernel(const float* __restrict__ in, unsigned short* __restrict__ out, int n4) {
    int i = blockIdx.x * blockDim.x + threadIdx.x;
    int stride = gridDim.x * blockDim.x;
    for (; i < n4; i += stride) {
        float4 v = reinterpret_cast<const float4*>(in)[i];
        ushort4 o;
        o.x = f2bf(v.x); o.y = f2bf(v.y); o.z = f2bf(v.z); o.w = f2bf(v.w);
        reinterpret_cast<ushort4*>(out)[i] = o;
    }
}

// ---------------- 256x256 fused GEMM (32x32x16 MFMA) + exp-sum + selected logit --------
// 4 phases per K-step, one K=16 slice each: {6 ds_read; 1 half-tile stage; bar;
// lgkm(0); 8 MFMA; bar}. LDS: 2xA + 3xB rotating (160 KiB). One vmcnt(4)/K-step.
__global__ __launch_bounds__(512, 2) void gemm_lse_kernel(
    const unsigned short* __restrict__ A,
    const unsigned short* __restrict__ W,
    const float* __restrict__ bias,
    const int* __restrict__ sel,
    float* __restrict__ partials,     // [M][NCB]
    float* __restrict__ sel_logit)    // [M]
{
    __shared__ __attribute__((aligned(128))) char lds[163840];  // A:0,32K  B:64K,96K,128K

    const int bid = blockIdx.x;
    const int swz = (bid & 7) * (NRB * NCB / 8) + (bid >> 3);   // 2000 % 8 == 0: bijective
    const int brow = swz % NRB;
    const int bcol = swz / NRB;
    const int tid  = threadIdx.x;
    const int lane = tid & 63;
    const int wv   = tid >> 6;
    const int wm   = wv >> 2;        // 0..1  row half (128 rows)
    const int wn   = wv & 3;         // 0..3  col quarter (64 cols)
    const int l31  = lane & 31, hi = lane >> 5;

    // ---- precomputed swizzled LDS read byte-offsets (within one 32KB buffer) ----
    // frag (row-tile, K=16 slice q): byte = row*128 + (((2q+hi) ^ (row&7)) << 4)
    int aOff[4][4];      // [mt][q]
    #pragma unroll
    for (int mt = 0; mt < 4; ++mt)
        #pragma unroll
        for (int q = 0; q < 4; ++q) {
            int row = wm * 128 + mt * 32 + l31;
            aOff[mt][q] = row * 128 + (((2 * q + hi) ^ (row & 7)) << 4);
        }
    int bOff[2][4];      // [nt][q]
    #pragma unroll
    for (int nt = 0; nt < 2; ++nt)
        #pragma unroll
        for (int q = 0; q < 4; ++q) {
            int row = wn * 64 + nt * 32 + l31;
            bOff[nt][q] = row * 128 + (((2 * q + hi) ^ (row & 7)) << 4);
        }

    // ---- stage lane offsets (elements); source granule inverse-swizzled ----
    int sLane[2][2];     // [i][half]
    #pragma unroll
    for (int i = 0; i < 2; ++i)
        #pragma unroll
        for (int h = 0; h < 2; ++h) {
            int c = i * 512 + tid;
            int r = (c >> 3) + h * 128;
            int gg = (c & 7) ^ (r & 7);
            sLane[i][h] = r * H_ + gg * 8;
        }

    const unsigned short* Ab = A + (long)brow * BM * H_;
    const unsigned short* Wb = W + (long)bcol * BN * H_;

    f32x16 acc[4][2] = {};
    short8 af[4], bf[2];

// dest bytes: bufoff + h*16384 + chunk*16 (chunk = i*512+tid); lane-affine (+16/lane)
#define STG(gb, bufoff, h, kt) \
    { _Pragma("unroll") \
      for (int i_ = 0; i_ < 2; ++i_) \
          gload_lds16((gb) + sLane[i_][h] + ((kt) & (H_ - 1)), \
                      (unsigned short*)(lds + (bufoff) + (h) * 16384 + (i_ * 512 + tid) * 16)); }

#define RDA(abase, q) \
    { _Pragma("unroll") \
      for (int mt_ = 0; mt_ < 4; ++mt_) \
          af[mt_] = *(const short8*)(lds + (abase) + aOff[mt_][q]); }

#define RDB(bbase, q) \
    { _Pragma("unroll") \
      for (int nt_ = 0; nt_ < 2; ++nt_) \
          bf[nt_] = *(const short8*)(lds + (bbase) + bOff[nt_][q]); }

#define MM() \
    __builtin_amdgcn_s_setprio(1); \
    _Pragma("unroll") \
    for (int mt_ = 0; mt_ < 4; ++mt_) \
    _Pragma("unroll") \
    for (int nt_ = 0; nt_ < 2; ++nt_) \
        acc[mt_][nt_] = __builtin_amdgcn_mfma_f32_32x32x16_bf16( \
            af[mt_], bf[nt_], acc[mt_][nt_], 0, 0, 0); \
    __builtin_amdgcn_s_setprio(0);

#define LGKM0   asm volatile("s_waitcnt lgkmcnt(0)" ::: "memory"); \
    __builtin_amdgcn_sched_barrier(0);
#define VMC(n)  asm volatile("s_waitcnt vmcnt(" #n ")" ::: "memory");
#define BAR     __builtin_amdgcn_s_barrier();
#define SCB     __builtin_amdgcn_sched_barrier(0);

    // ---- prologue: A(0)->a0, B(0)->b0, B(1)->b1 ----
    STG(Ab, 0, 0, 0)      STG(Ab, 0, 1, 0)
    STG(Wb, 65536, 0, 0)  STG(Wb, 65536, 1, 0)
    STG(Wb, 98304, 0, 64) STG(Wb, 98304, 1, 64)
    VMC(4)                      // A(0),B(0) landed; B(1) may fly
    BAR
    SCB

    int aR = 0,     aW = 32768;                    // A: read / write(stage t+1)
    int bR = 65536, bN = 98304, bW = 131072;       // B: read(t) / next(t+1) / write(t+2)
    int ktA = 64, ktB = 128;

    for (int t = 0; t < NT; ++t) {
        // q0: slice 0 ; stage A(t+1)h0
        RDA(aR, 0) RDB(bR, 0)
        STG(Ab, aW, 0, ktA)
        BAR
        LGKM0
        MM()
        BAR
        // q1: slice 1 ; stage A(t+1)h1
        RDA(aR, 1) RDB(bR, 1)
        STG(Ab, aW, 1, ktA)
        BAR
        LGKM0
        MM()
        BAR
        // q2: slice 2 ; stage B(t+2)h0
        RDA(aR, 2) RDB(bR, 2)
        STG(Wb, bW, 0, ktB)
        BAR
        LGKM0
        MM()
        BAR
        // q3: slice 3 ; stage B(t+2)h1 ; counted boundary wait:
        // newest 4 vm-ops = B(t+2) -> forces A(t+1), B(t+1) landed before next q0.
        RDA(aR, 3) RDB(bR, 3)
        STG(Wb, bW, 1, ktB)
        VMC(4)
        BAR
        LGKM0
        MM()
        BAR

        int ta = aR; aR = aW; aW = ta;
        int tb = bR; bR = bN; bN = bW; bW = tb;
        ktA += 64; ktB += 64;
    }

    VMC(0)
    __syncthreads();

    // ---- epilogue: bias, exp, per-row partial sums, selected logit ----
    // 32x32 C/D layout: col = lane&31, row = (reg&3) + 8*(reg>>2) + 4*(lane>>5)
    float* sums = (float*)lds;                     // [256][4], LDS now free
    const int colb = bcol * BN + wn * 64 + l31;    // + nt*32
    float bv[2] = { bias[colb], bias[colb + 32] };

    #pragma unroll
    for (int mt = 0; mt < 4; ++mt) {
        #pragma unroll
        for (int reg = 0; reg < 16; ++reg) {
            const int rl = wm * 128 + mt * 32 + (reg & 3) + 8 * (reg >> 2) + 4 * hi;
            const long grow = (long)brow * BM + rl;
            const int stok = sel[grow];
            float s = 0.f;
            #pragma unroll
            for (int nt = 0; nt < 2; ++nt) {
                float logit = acc[mt][nt][reg] + bv[nt];
                s += __expf(logit);
                if (stok == colb + nt * 32) sel_logit[grow] = logit;
            }
            s += __shfl_xor(s, 1); s += __shfl_xor(s, 2);
            s += __shfl_xor(s, 4); s += __shfl_xor(s, 8);
            s += __shfl_xor(s, 16);
            if (l31 == 0) sums[rl * 4 + wn] = s;
        }
    }
    __syncthreads();
    if (tid < BM) {
        float tot = sums[tid * 4 + 0] + sums[tid * 4 + 1] + sums[tid * 4 + 2] + sums[tid * 4 + 3];
        partials[((long)brow * BM + tid) * NCB + bcol] = tot;
    }
#undef STG
#undef RDA
#undef RDB
#undef MM
#undef LGKM0
#undef VMC
#undef BAR
#undef SCB
}

// ---------------- per-row reduce: partials -> per-token logp ----------------
__global__ void reduce_lse_kernel(const float* __restrict__ partials,
                                  const float* __restrict__ sel_logit,
                                  float* __restrict__ lp) {
    const int row = blockIdx.x;
    const int lane = threadIdx.x;   // 64
    float s = 0.f;
    for (int i = lane; i < NCB; i += 64) s += partials[(long)row * NCB + i];
    #pragma unroll
    for (int o = 32; o; o >>= 1) s += __shfl_xor(s, o);
    if (lane == 0) lp[row] = sel_logit[row] - __logf(s);
}

// ---------------- final GSPO loss (one block) ----------------
__device__ __forceinline__ float block_sum(float v, float* red) {
    const int lane = threadIdx.x & 63, wid = threadIdx.x >> 6;
    #pragma unroll
    for (int o = 32; o; o >>= 1) v += __shfl_xor(v, o);
    if (lane == 0) red[wid] = v;
    __syncthreads();
    if (wid == 0) {
        float x = (lane < 16) ? red[lane] : 0.f;
        #pragma unroll
        for (int o = 8; o; o >>= 1) x += __shfl_xor(x, o);
        if (lane == 0) red[0] = x;
    }
    __syncthreads();
    float r = red[0];
    __syncthreads();
    return r;
}

__global__ __launch_bounds__(1024) void loss_kernel(
    const float* __restrict__ lp, const float* __restrict__ mask,
    const float* __restrict__ adv, const float* __restrict__ ref,
    const float* __restrict__ old, float* __restrict__ out) {
    __shared__ float red[16];
    const int s = threadIdx.x;
    float loss_acc = 0.f;
    for (int b = 0; b < 4; ++b) {
        const int i = b * S_ + s;
        const float mk = mask[i];
        const float lpv = lp[i];
        const float lrsum = block_sum((lpv - old[i]) * mk, red);
        const float msum  = block_sum(mk, red);
        const float seqlen = fmaxf(msum, 1.f);
        const float sw = lrsum / seqlen;
        const float c1 = __expf(sw);
        const float c2 = fminf(fmaxf(c1, 1.f - EPS_LOW_C), 1.f + EPS_HIGH_C);
        const float a = adv[b];
        const float pmin = fminf(c1 * a, c2 * a);
        const float d = ref[i] - lpv;
        const float ptl = -pmin + BETA_C * (__expf(d) - d - 1.f);
        const float lsum = block_sum(ptl * mk, red);
        loss_acc += lsum / seqlen;
    }
    if (s == 0) out[0] = loss_acc * (1.f / (float)B_);
}

extern "C" void kernel_launch(void* const* d_in, const int* in_sizes, int n_in,
                              void* d_out, int out_size, void* d_ws, size_t ws_size,
                              hipStream_t stream) {
    const float* x    = (const float*)d_in[0];
    const float* W    = (const float*)d_in[1];
    const float* bias = (const float*)d_in[2];
    const int*   sel  = (const int*)d_in[3];
    const float* mask = (const float*)d_in[4];
    const float* adv  = (const float*)d_in[5];
    const float* ref  = (const float*)d_in[6];
    const float* old  = (const float*)d_in[7];
    float* out = (float*)d_out;

    char* ws = (char*)d_ws;
    unsigned short* Abf = (unsigned short*)ws;                        // 16,777,216 B
    unsigned short* Wbf = (unsigned short*)(ws + 16777216);           // 131,072,000 B
    float* partials  = (float*)(ws + 16777216 + 131072000);           // 2,048,000 B
    float* sel_logit = (float*)(ws + 16777216 + 131072000 + 2048000);
    float* lp        = sel_logit + M_;

    cvt_kernel<<<2048, 256, 0, stream>>>(x, Abf, M_ * H_ / 4);
    cvt_kernel<<<4096, 256, 0, stream>>>(W, Wbf, V_ * H_ / 4);

    gemm_lse_kernel<<<NRB * NCB, 512, 0, stream>>>(Abf, Wbf, bias, sel, partials, sel_logit);

    reduce_lse_kernel<<<M_, 64, 0, stream>>>(partials, sel_logit, lp);
    loss_kernel<<<1, 1024, 0, stream>>>(lp, mask, adv, ref, old, out);
}

// Round 9
// 554.295 us; speedup vs baseline: 1.2387x; 1.2387x over previous
//
#include <hip/hip_runtime.h>
#include <hip/hip_bf16.h>

#define BETA_C 0.04f
#define EPS_LOW_C 0.2f
#define EPS_HIGH_C 0.2f

static constexpr int B_ = 4, S_ = 1024, H_ = 2048, V_ = 32000;
static constexpr int M_ = B_ * S_;          // 4096 token rows
static constexpr int BM = 256, BN = 256, BK = 64;
static constexpr int NRB = M_ / BM;         // 16
static constexpr int NCB = V_ / BN;         // 125
static constexpr int NT  = H_ / BK;         // 32 K-steps

typedef __attribute__((ext_vector_type(8))) short short8;
typedef __attribute__((ext_vector_type(4))) float f32x4;

__device__ __forceinline__ unsigned short f2bf(float f) {
    unsigned u = __builtin_bit_cast(unsigned, f);
    unsigned r = 0x7FFFu + ((u >> 16) & 1u);
    return (unsigned short)((u + r) >> 16);
}

__device__ __forceinline__ void gload_lds16(const unsigned short* g, unsigned short* l) {
    __builtin_amdgcn_global_load_lds(
        (const __attribute__((address_space(1))) unsigned int*)g,
        (__attribute__((address_space(3))) unsigned int*)l, 16, 0, 0);
}

// ---------------- fp32 -> bf16 conversion ----------------
__global__ void cvt_kernel(const float* __restrict__ in, unsigned short* __restrict__ out, int n4) {
    int i = blockIdx.x * blockDim.x + threadIdx.x;
    int stride = gridDim.x * blockDim.x;
    for (; i < n4; i += stride) {
        float4 v = reinterpret_cast<const float4*>(in)[i];
        ushort4 o;
        o.x = f2bf(v.x); o.y = f2bf(v.y); o.z = f2bf(v.z); o.w = f2bf(v.w);
        reinterpret_cast<ushort4*>(out)[i] = o;
    }
}

// ---------------- 256x256 fused GEMM (16x16x32) + exp-sum + selected logit --------
// Fully-unrolled K-loop (constexpr offsets). Every s_barrier is followed by
// sched_barrier(0) (s_barrier is NOT a compiler fence). Round-8 bug fixed:
// B region base (65536) lives ONLY in the buffer constants bR/bW, not in bBase
// (it was double-counted -> reads past LDS -> NaN).
__global__ __launch_bounds__(512, 2) void gemm_lse_kernel(
    const unsigned short* __restrict__ A,
    const unsigned short* __restrict__ W,
    const float* __restrict__ bias,
    const int* __restrict__ sel,
    float* __restrict__ partials,     // [M][NCB]
    float* __restrict__ sel_logit)    // [M]
{
    __shared__ __attribute__((aligned(128))) char lds[163840];

    const int bid = blockIdx.x;
    const int swz = (bid & 7) * (NRB * NCB / 8) + (bid >> 3);   // 2000 % 8 == 0: bijective
    const int brow = swz % NRB;
    const int bcol = swz / NRB;
    const int tid  = threadIdx.x;
    const int lane = tid & 63;
    const int wv   = tid >> 6;
    const int wm   = wv >> 2;        // 0..1  row half
    const int wn   = wv & 3;         // 0..3  col quarter
    const int l15  = lane & 15, lg = lane >> 4;

    // ---- per-lane base byte-offsets (loop-invariant; all else constexpr) ----
    // A read addr = aR + m8*2048 + aBase[ks]      (aR in {0, 32768})
    // B read addr = bR + n*2048  + bBase[ks]      (bR in {65536, 98304, 131072})
    int aBase[2], bBase[2];
    #pragma unroll
    for (int ks = 0; ks < 2; ++ks) {
        const int sw = ((ks * 4 + lg) ^ (l15 & 7)) << 4;
        aBase[ks] = (wm * 128 + l15) * 128 + sw;
        bBase[ks] = (wn * 64 + l15) * 128 + sw;    // NO region base here (round-8 fix)
    }
    // stage per-lane global byte offsets; source granule inverse-swizzled
    int sByte[2][2];     // [i][half]
    #pragma unroll
    for (int i = 0; i < 2; ++i)
        #pragma unroll
        for (int h = 0; h < 2; ++h) {
            int c = i * 512 + tid;
            int r = (c >> 3) + h * 128;
            int gg = (c & 7) ^ (r & 7);
            sByte[i][h] = (r * H_ + gg * 8) * 2;
        }

    const unsigned short* Ab = A + (long)brow * BM * H_;
    const unsigned short* Wb = W + (long)bcol * BN * H_;

    f32x4 acc[8][4] = {};
    short8 af[2][2], bfr[4][2];

#define STG(gb, bufoff, h, kt) \
    { _Pragma("unroll") \
      for (int i_ = 0; i_ < 2; ++i_) \
          gload_lds16((const unsigned short*)((const char*)(gb) + sByte[i_][h] + (kt) * 2), \
                      (unsigned short*)(lds + (bufoff) + (h) * 16384 + (i_ * 512 + tid) * 16)); }

#define RDA(abuf, q) \
    { _Pragma("unroll") \
      for (int mi_ = 0; mi_ < 2; ++mi_) \
      _Pragma("unroll") \
      for (int ks_ = 0; ks_ < 2; ++ks_) \
          af[mi_][ks_] = *(const short8*)(lds + (abuf) + ((q) * 2 + mi_) * 2048 + aBase[ks_]); }

#define RDB(bbuf) \
    { _Pragma("unroll") \
      for (int n_ = 0; n_ < 4; ++n_) \
      _Pragma("unroll") \
      for (int ks_ = 0; ks_ < 2; ++ks_) \
          bfr[n_][ks_] = *(const short8*)(lds + (bbuf) + n_ * 2048 + bBase[ks_]); }

#define MM(q) \
    __builtin_amdgcn_s_setprio(1); \
    _Pragma("unroll") \
    for (int ks_ = 0; ks_ < 2; ++ks_) \
    _Pragma("unroll") \
    for (int mi_ = 0; mi_ < 2; ++mi_) \
    _Pragma("unroll") \
    for (int n_ = 0; n_ < 4; ++n_) \
        acc[(q) * 2 + mi_][n_] = __builtin_amdgcn_mfma_f32_16x16x32_bf16( \
            af[mi_][ks_], bfr[n_][ks_], acc[(q) * 2 + mi_][n_], 0, 0, 0); \
    __builtin_amdgcn_s_setprio(0);

#define LGKM(n) asm volatile("s_waitcnt lgkmcnt(" #n ")" ::: "memory");
#define LGKM0   asm volatile("s_waitcnt lgkmcnt(0)" ::: "memory"); \
    __builtin_amdgcn_sched_barrier(0);
#define VMC(n)  asm volatile("s_waitcnt vmcnt(" #n ")" ::: "memory");
// s_barrier + full scheduling fence: nothing (esp. ds_reads) may cross.
#define BAR     { __builtin_amdgcn_s_barrier(); __builtin_amdgcn_sched_barrier(0); }

    // ---- prologue: A(0)->a0, B(0)->b0, B(1)->b1 ----
    STG(Ab, 0, 0, 0)       STG(Ab, 0, 1, 0)
    STG(Wb, 65536, 0, 0)   STG(Wb, 65536, 1, 0)
    STG(Wb, 98304, 0, 64)  STG(Wb, 98304, 1, 64)
    VMC(4)                      // A(0),B(0) landed; B(1) may fly
    BAR

    #pragma unroll
    for (int t = 0; t < NT; ++t) {
        const int aR = (t & 1) * 32768;               // A read buf (t)
        const int aW = ((t + 1) & 1) * 32768;         // A write buf (t+1)
        const int bR = 65536 + (t % 3) * 32768;       // B read buf (t)
        const int bW = 65536 + ((t + 2) % 3) * 32768; // B write buf (t+2)
        const int ktA = ((t + 1) * BK) & (H_ - 1);    // elements; tail wraps (dead-safe)
        const int ktB = ((t + 2) * BK) & (H_ - 1);

        // Q1: B(t) all + A(t) q0 ; stage A(t+1)h0
        RDB(bR) RDA(aR, 0)
        STG(Ab, aW, 0, ktA)
        LGKM(8)
        BAR
        LGKM0
        MM(0)
        BAR
        // Q2: A q1 ; stage A(t+1)h1
        RDA(aR, 1)
        STG(Ab, aW, 1, ktA)
        BAR
        LGKM0
        MM(1)
        BAR
        // Q3: A q2 ; stage B(t+2)h0
        RDA(aR, 2)
        STG(Wb, bW, 0, ktB)
        BAR
        LGKM0
        MM(2)
        BAR
        // Q4: A q3 ; stage B(t+2)h1 ; counted boundary wait:
        // newest 4 vm-ops = B(t+2) -> forces A(t+1), B(t+1) landed before next Q1.
        RDA(aR, 3)
        STG(Wb, bW, 1, ktB)
        VMC(4)
        BAR
        LGKM0
        MM(3)
        BAR
    }

    VMC(0)
    __syncthreads();

    // ---- epilogue: bias, exp, per-row partial sums, selected logit ----
    float* sums = (float*)lds;                     // [256][4], LDS now free
    const int colb = bcol * BN + wn * 64 + l15;    // + n*16
    float bv[4];
    #pragma unroll
    for (int n = 0; n < 4; ++n) bv[n] = bias[colb + n * 16];

    #pragma unroll
    for (int m = 0; m < 8; ++m) {
        #pragma unroll
        for (int j = 0; j < 4; ++j) {
            const long grow = (long)brow * BM + wm * 128 + m * 16 + lg * 4 + j;
            const int stok = sel[grow];
            float s = 0.f;
            #pragma unroll
            for (int n = 0; n < 4; ++n) {
                float logit = acc[m][n][j] + bv[n];
                s += __expf(logit);
                if (stok == colb + n * 16) sel_logit[grow] = logit;
            }
            s += __shfl_xor(s, 1); s += __shfl_xor(s, 2);
            s += __shfl_xor(s, 4); s += __shfl_xor(s, 8);
            if (l15 == 0) sums[(wm * 128 + m * 16 + lg * 4 + j) * 4 + wn] = s;
        }
    }
    __syncthreads();
    if (tid < BM) {
        float tot = sums[tid * 4 + 0] + sums[tid * 4 + 1] + sums[tid * 4 + 2] + sums[tid * 4 + 3];
        partials[((long)brow * BM + tid) * NCB + bcol] = tot;
    }
#undef STG
#undef RDA
#undef RDB
#undef MM
#undef LGKM
#undef LGKM0
#undef VMC
#undef BAR
}

// ---------------- per-row reduce: partials -> per-token logp ----------------
__global__ void reduce_lse_kernel(const float* __restrict__ partials,
                                  const float* __restrict__ sel_logit,
                                  float* __restrict__ lp) {
    const int row = blockIdx.x;
    const int lane = threadIdx.x;   // 64
    float s = 0.f;
    for (int i = lane; i < NCB; i += 64) s += partials[(long)row * NCB + i];
    #pragma unroll
    for (int o = 32; o; o >>= 1) s += __shfl_xor(s, o);
    if (lane == 0) lp[row] = sel_logit[row] - __logf(s);
}

// ---------------- final GSPO loss (one block) ----------------
__device__ __forceinline__ float block_sum(float v, float* red) {
    const int lane = threadIdx.x & 63, wid = threadIdx.x >> 6;
    #pragma unroll
    for (int o = 32; o; o >>= 1) v += __shfl_xor(v, o);
    if (lane == 0) red[wid] = v;
    __syncthreads();
    if (wid == 0) {
        float x = (lane < 16) ? red[lane] : 0.f;
        #pragma unroll
        for (int o = 8; o; o >>= 1) x += __shfl_xor(x, o);
        if (lane == 0) red[0] = x;
    }
    __syncthreads();
    float r = red[0];
    __syncthreads();
    return r;
}

__global__ __launch_bounds__(1024) void loss_kernel(
    const float* __restrict__ lp, const float* __restrict__ mask,
    const float* __restrict__ adv, const float* __restrict__ ref,
    const float* __restrict__ old, float* __restrict__ out) {
    __shared__ float red[16];
    const int s = threadIdx.x;
    float loss_acc = 0.f;
    for (int b = 0; b < 4; ++b) {
        const int i = b * S_ + s;
        const float mk = mask[i];
        const float lpv = lp[i];
        const float lrsum = block_sum((lpv - old[i]) * mk, red);
        const float msum  = block_sum(mk, red);
        const float seqlen = fmaxf(msum, 1.f);
        const float sw = lrsum / seqlen;
        const float c1 = __expf(sw);
        const float c2 = fminf(fmaxf(c1, 1.f - EPS_LOW_C), 1.f + EPS_HIGH_C);
        const float a = adv[b];
        const float pmin = fminf(c1 * a, c2 * a);
        const float d = ref[i] - lpv;
        const float ptl = -pmin + BETA_C * (__expf(d) - d - 1.f);
        const float lsum = block_sum(ptl * mk, red);
        loss_acc += lsum / seqlen;
    }
    if (s == 0) out[0] = loss_acc * (1.f / (float)B_);
}

extern "C" void kernel_launch(void* const* d_in, const int* in_sizes, int n_in,
                              void* d_out, int out_size, void* d_ws, size_t ws_size,
                              hipStream_t stream) {
    const float* x    = (const float*)d_in[0];
    const float* W    = (const float*)d_in[1];
    const float* bias = (const float*)d_in[2];
    const int*   sel  = (const int*)d_in[3];
    const float* mask = (const float*)d_in[4];
    const float* adv  = (const float*)d_in[5];
    const float* ref  = (const float*)d_in[6];
    const float* old  = (const float*)d_in[7];
    float* out = (float*)d_out;

    char* ws = (char*)d_ws;
    unsigned short* Abf = (unsigned short*)ws;                        // 16,777,216 B
    unsigned short* Wbf = (unsigned short*)(ws + 16777216);           // 131,072,000 B
    float* partials  = (float*)(ws + 16777216 + 131072000);           // 2,048,000 B
    float* sel_logit = (float*)(ws + 16777216 + 131072000 + 2048000);
    float* lp        = sel_logit + M_;

    cvt_kernel<<<2048, 256, 0, stream>>>(x, Abf, M_ * H_ / 4);
    cvt_kernel<<<4096, 256, 0, stream>>>(W, Wbf, V_ * H_ / 4);

    gemm_lse_kernel<<<NRB * NCB, 512, 0, stream>>>(Abf, Wbf, bias, sel, partials, sel_logit);

    reduce_lse_kernel<<<M_, 64, 0, stream>>>(partials, sel_logit, lp);
    loss_kernel<<<1, 1024, 0, stream>>>(lp, mask, adv, ref, old, out);
}